// Round 1
// 72.068 us; speedup vs baseline: 1.0538x; 1.0538x over previous
//
#include <hip/hip_runtime.h>
#include <math.h>

// Problem constants (fixed by setup_inputs in the reference):
//   features: [B=2, C=512, H=50, W=64] float32
//   roiss:    [B=2, N=128, 4]          float32  (x1,y1,x2,y2 pixel coords)
//   out:      [B, N, C]                float32
#define IMG_W_F 1024.0f
#define IMG_H_F 800.0f

// One block = (one ROI, 128 channels); thread = one channel.
// grid = (B*N, C/128) = 1024 blocks, 128 threads (2 waves) each.
//
// Key change vs previous version: region extents are provably <= 7x7 for this
// input distribution (box sides 20..84 px at 1/16 scale -> ceil(5.25+frac)<=7),
// so the y/x loops are fully unrolled with UNIFORM (block-wide) guards and the
// region is fetched as <=7 rows x <=3 aligned float4 loads, all independent and
// in flight together -> one memory latency instead of ~16 serial L2-hit
// latencies, and 4x fewer divergent-address VMEM instructions.
__global__ __launch_bounds__(128) void roipool_kernel(
    const float* __restrict__ feat,   // [B, C, H, W]
    const float* __restrict__ rois,   // [B, N, 4]
    float* __restrict__ out,          // [B, N, C]
    int C, int H, int W, int N)
{
    const int bn = blockIdx.x;            // b * N + n
    const int b  = bn / N;

    // ---- box math: replicate reference fp32 op order exactly (R1-verified) ----
    const float* roi = rois + (size_t)bn * 4;
    const float rx1 = roi[0], ry1 = roi[1], rx2 = roi[2], ry2 = roi[3];

    int x1 = (int)floorf(rx1 / IMG_W_F * (float)W);
    int y1 = (int)floorf(ry1 / IMG_H_F * (float)H);
    int x2 = (int)ceilf (rx2 / IMG_W_F * (float)W);
    int y2 = (int)ceilf (ry2 / IMG_H_F * (float)H);
    x1 = max(x1, 0);
    y1 = max(y1, 0);
    x2 = max(x2, 0);
    y2 = max(y2, 0);
    if (x1 == 0 && x2 == 0) x2 = 1;     // degenerate-box fixes, reference order
    if (y1 == 0 && y2 == 0) y2 = 1;
    if (x1 >= W) x1 = W - 1;
    if (y1 >= H) y1 = H - 1;
    const int ye = min(y2, H);
    const int xe = min(x2, W);

    const int c = blockIdx.y * 128 + threadIdx.x;   // one channel per thread
    const float* fc = feat + ((size_t)b * C + c) * (H * W);

    const int rows = ye - y1;           // 1..7 for this distribution
    const int a    = x1 & ~3;           // 16B-aligned start column (>= 0)
    // number of aligned float4 blocks covering [x1, xe): 1..3.
    // Any 4-aligned block containing a needed cell ends at column <= 63 (W=64
    // is a multiple of 4), so these loads never cross the row end -> no OOB.
    const int nb   = ((x1 - a) + (xe - x1) + 3) >> 2;

    float m = -INFINITY;

    if (rows <= 7 && nb <= 3) {
        // ---- stage: all loads issued before any use (static indexing only) ----
        float4 v0[7], v1[7], v2[7];
        #pragma unroll
        for (int dy = 0; dy < 7; ++dy) {
            if (dy < rows) {                       // block-uniform branch
                const float* fr = fc + (y1 + dy) * W + a;
                v0[dy] = *reinterpret_cast<const float4*>(fr);
                if (nb > 1) v1[dy] = *reinterpret_cast<const float4*>(fr + 4);
                if (nb > 2) v2[dy] = *reinterpret_cast<const float4*>(fr + 8);
            }
        }
        // ---- fold rows (vertical max), guards identical to the load guards ----
        float4 c0 = make_float4(-INFINITY, -INFINITY, -INFINITY, -INFINITY);
        float4 c1 = c0, c2 = c0;
        #pragma unroll
        for (int dy = 0; dy < 7; ++dy) {
            if (dy < rows) {
                c0.x = fmaxf(c0.x, v0[dy].x);
                c0.y = fmaxf(c0.y, v0[dy].y);
                c0.z = fmaxf(c0.z, v0[dy].z);
                c0.w = fmaxf(c0.w, v0[dy].w);
                if (nb > 1) {
                    c1.x = fmaxf(c1.x, v1[dy].x);
                    c1.y = fmaxf(c1.y, v1[dy].y);
                    c1.z = fmaxf(c1.z, v1[dy].z);
                    c1.w = fmaxf(c1.w, v1[dy].w);
                }
                if (nb > 2) {
                    c2.x = fmaxf(c2.x, v2[dy].x);
                    c2.y = fmaxf(c2.y, v2[dy].y);
                    c2.z = fmaxf(c2.z, v2[dy].z);
                    c2.w = fmaxf(c2.w, v2[dy].w);
                }
            }
        }
        // ---- fold columns with validity mask (uniform; pad cells excluded) ----
        const float cm[12] = {c0.x, c0.y, c0.z, c0.w,
                              c1.x, c1.y, c1.z, c1.w,
                              c2.x, c2.y, c2.z, c2.w};
        #pragma unroll
        for (int i = 0; i < 12; ++i) {
            const int xc = a + i;
            if (xc >= x1 && xc < xe) m = fmaxf(m, cm[i]);
        }
    } else {
        // Fallback (never taken for this input distribution; kept for safety)
        for (int y = y1; y < ye; ++y) {
            const float* fr = fc + y * W;
            for (int x = x1; x < xe; ++x) m = fmaxf(m, fr[x]);
        }
    }

    out[(size_t)bn * C + c] = m;        // coalesced 128-wide store
}

extern "C" void kernel_launch(void* const* d_in, const int* in_sizes, int n_in,
                              void* d_out, int out_size, void* d_ws, size_t ws_size,
                              hipStream_t stream) {
    const int B = 2, C = 512, H = 50, W = 64, N = 128;

    const float* feat = (const float*)d_in[0];
    const float* rois = (const float*)d_in[1];
    float* out = (float*)d_out;

    dim3 grid(B * N, C / 128);   // 256 x 4 = 1024 blocks
    dim3 block(128);             // thread = one channel
    roipool_kernel<<<grid, block, 0, stream>>>(feat, rois, out, C, H, W, N);
}